// Round 6
// baseline (1177.020 us; speedup 1.0000x reference)
//
#include <hip/hip_runtime.h>
#include <math.h>

// Fused Conv2d(64->128,3x3,valid) + bias + min(oc) + tanh(tanh()) via
// bf16 MFMA implicit GEMM (mfma_f32_32x32x16_bf16).
//
// Round 11: producer/consumer wave specialization.
//  Rule learned (rounds 7/8/10): staged data must NEVER be register-resident
//  across the K-loop in program order — the compiler spills it to scratch.
//  Fix: put the staging loads in DIFFERENT WAVES than the MFMAs.
//  - 512 threads = 8 waves: waves 0-3 consumers (round-6 K-loop + round-10
//    butterfly epilogue, both harness-verified), waves 4-7 producers.
//  - Producers stage the 2 new input rows of the 6-slot rolling ring each
//    iteration (issue loads right after bar2, write when they land, sleep
//    at bar1) — their HBM latency runs concurrently with the consumers'
//    4608-cycle MFMA loop. Slot-disjointness as in round 10.
//  - launch_bounds(512,4): VGPR cap 128 (consumer branch measured ~84),
//    2 blocks/CU (LDS 51.7KB). Grid (4,8,16) = 512 blocks = exactly 2/CU;
//    16 oh-pairs per block.
// LDS: xt[6 slot][8 g][66 col][8 j] bf16 = 50688 B + obuf 1KB.

typedef __attribute__((ext_vector_type(8))) short bf16x8;
typedef __attribute__((ext_vector_type(16))) float f32x16;

static __device__ __forceinline__ short f2bf(float f) {
    unsigned u = __float_as_uint(f);
    u += 0x7fffu + ((u >> 16) & 1u);
    return (short)(u >> 16);
}

// v_cvt_pk_bf16_f32: D[15:0]=bf16(a), D[31:16]=bf16(b), round-nearest-even.
static __device__ __forceinline__ unsigned cvt_pk_bf16(float a, float b) {
    unsigned r;
    asm("v_cvt_pk_bf16_f32 %0, %1, %2" : "=v"(r) : "v"(a), "v"(b));
    return r;
}

// d_ws layout: bf16 bits, idx = ((kstep*2 + hi)*128 + oc)*8 + j
// kstep = tap*4 + icc, tap = kh*3 + kw, ic = icc*16 + hi*8 + j. 73728 elems.
__global__ void wtrans(const float* __restrict__ wg, short* __restrict__ wsB) {
    int o4 = blockIdx.x * 256 + threadIdx.x;   // 0..18431 (x4 elements)
    if (o4 >= 18432) return;
    float4 v = ((const float4*)wg)[o4];        // coalesced read
    float f[4] = {v.x, v.y, v.z, v.w};
    int base = o4 * 4;
    #pragma unroll
    for (int q = 0; q < 4; ++q) {
        int e  = base + q;                     // ((oc*64+ic)*3+kh)*3+kw
        int kw = e % 3, r1 = e / 3;
        int kh = r1 % 3, r2 = r1 / 3;
        int ic = r2 & 63, oc = r2 >> 6;
        int tap = kh * 3 + kw;
        int icc = ic >> 4, hi = (ic >> 3) & 1, j = ic & 7;
        int kstep = tap * 4 + icc;
        wsB[((kstep * 2 + hi) * 128 + oc) * 8 + j] = f2bf(f[q]);
    }
}

// Stage ONE input row (global row rg): 8 g-groups x 66 cols = 528 bf16x8.
// Executed by the 256 producer threads (ptid 0..255); <=3 batches each.
#define STAGE1_ISSUE(rg, fbuf)                                                \
    _Pragma("unroll")                                                         \
    for (int s = 0; s < 3; ++s) {                                             \
        int idx = s * 256 + ptid;                                             \
        if (idx < 528) {                                                      \
            int g = idx / 66, col = idx - g * 66;                             \
            int icc = g >> 1, hie = g & 1;                                    \
            int iw = ow0 + col;                                               \
            const float* src = xg +                                           \
                (((size_t)(b * 64 + icc * 16 + hie * 8) * 256) + (rg)) * 256 + iw; \
            bool valid = iw < 256;                                            \
            _Pragma("unroll")                                                 \
            for (int j = 0; j < 8; ++j) fbuf[s][j] = valid ? src[j * 65536] : 0.f; \
        }                                                                     \
    }

#define STAGE1_WRITE(ss, fbuf)                                                \
    _Pragma("unroll")                                                         \
    for (int s = 0; s < 3; ++s) {                                             \
        int idx = s * 256 + ptid;                                             \
        if (idx < 528) {                                                      \
            int g = idx / 66, col = idx - g * 66;                             \
            int icc = g >> 1, hie = g & 1;                                    \
            bf16x8 vv;                                                        \
            unsigned* vp = (unsigned*)&vv;                                    \
            _Pragma("unroll")                                                 \
            for (int p = 0; p < 4; ++p)                                       \
                vp[p] = cvt_pk_bf16(fbuf[s][2 * p], fbuf[s][2 * p + 1]);      \
            *(bf16x8*)(xt + ((ss) * 8 + icc * 2 + hie) * 528 + col * 8) = vv; \
        }                                                                     \
    }

__global__ __launch_bounds__(512, 4)
void conv_min_tanh_mfma(const float* __restrict__ xg,
                        const short* __restrict__ wsB,
                        const float* __restrict__ bg,
                        float* __restrict__ out) {
    __shared__ __align__(16) short xt[25344];  // 6 slots x 8 g x 528 = 50688 B
    __shared__ float obuf[256];                // [2 nh][128 px]

    const int tid  = threadIdx.x;
    const int w    = tid >> 6;
    const bool producer = (w >= 4);
    const int ptid = tid & 255;                // producer thread id (w>=4)
    const int lane = tid & 63, l31 = lane & 31, hi = lane >> 5;
    const int r    = w & 1;        // consumer: output row within pair
    const int nh   = (w >> 1) & 1; // consumer: oc half
    const int ow0  = blockIdx.x * 64;
    const int b    = blockIdx.z;
    const int p0   = blockIdx.y * 16;          // first oh-pair
    const int np   = min(16, 127 - p0);        // pairs this block owns
    const int ih0  = p0 * 2;                   // first input row

    const bf16x8* bbase = (const bf16x8*)(wsB + ((size_t)hi * 128 + nh * 64 + l31) * 8);
    bf16x8 bc0, bc1, bd0, bd1;                 // consumer B pipeline state
    float bv0 = 0.f, bv1 = 0.f;

    // ---- prologue
    if (producer) {
        // stage input rows ih0..ih0+3 -> slots 0..3
        float fP[3][8], fQ[3][8];
        STAGE1_ISSUE(ih0 + 0, fP)
        STAGE1_ISSUE(ih0 + 1, fQ)
        STAGE1_WRITE(0, fP)
        STAGE1_WRITE(1, fQ)
        STAGE1_ISSUE(ih0 + 2, fP)
        STAGE1_ISSUE(ih0 + 3, fQ)
        STAGE1_WRITE(2, fP)
        STAGE1_WRITE(3, fQ)
    } else {
        // prime B pipeline (k=0, k=1) and bias while producers stage
        bc0 = bbase[0];   bc1 = bbase[32];
        bd0 = bbase[256]; bd1 = bbase[256 + 32];
        bv0 = bg[nh * 64 + l31];
        bv1 = bg[nh * 64 + 32 + l31];
    }
    __syncthreads();

    int s0 = 0;                    // window base slot (even: 0,2,4 cycle)

    for (int it = 0; it < np; ++it) {
        const bool do_stage = (it < np - 1);

        if (producer) {
            // stage rows 2it+4, 2it+5 into slots (s0+4)%6, (s0+4)%6+1.
            // Loads issued right after bar2; latency runs under the
            // consumers' K-loop. Write slots disjoint from read slots.
            if (do_stage) {
                int sA = s0 + 4; if (sA >= 6) sA -= 6;   // even: 4,0,2
                float fP[3][8], fQ[3][8];
                STAGE1_ISSUE(ih0 + 2 * it + 4, fP)
                STAGE1_ISSUE(ih0 + 2 * it + 5, fQ)
                STAGE1_WRITE(sA, fP)
                STAGE1_WRITE(sA + 1, fQ)
            }
        } else {
            // ---- consumer K-loop on resident slots (s0+r .. s0+r+2)
            int sr0 = s0 + r;     if (sr0 >= 6) sr0 -= 6;
            int sr1 = s0 + r + 1; if (sr1 >= 6) sr1 -= 6;
            int sr2 = s0 + r + 2; if (sr2 >= 6) sr2 -= 6;
            const bf16x8* bp0 = (const bf16x8*)(xt + (sr0 * 8 + hi) * 528 + l31 * 8);
            const bf16x8* bp1 = (const bf16x8*)(xt + (sr1 * 8 + hi) * 528 + l31 * 8);
            const bf16x8* bp2 = (const bf16x8*)(xt + (sr2 * 8 + hi) * 528 + l31 * 8);

            f32x16 acc00 = {}, acc01 = {}, acc10 = {}, acc11 = {};
            bf16x8 a0 = bp0[0], a1 = bp0[32];      // k=0 (tap0, icc0)

            #pragma unroll
            for (int k = 0; k < 36; ++k) {
                // A prefetch for k+1 (2 ds_read_b128)
                bf16x8 an0 = a0, an1 = a1;
                if (k < 35) {
                    const int kn = k + 1, tapn = kn >> 2, iccn = kn & 3;
                    const int khn = tapn / 3, kwn = tapn - khn * 3;
                    const bf16x8* bp = (khn == 0) ? bp0 : (khn == 1) ? bp1 : bp2;
                    an0 = bp[iccn * 132 + kwn];
                    an1 = bp[iccn * 132 + kwn + 32];
                }
                // B prefetch distance 2
                bf16x8 be0 = bd0, be1 = bd1;
                if (k < 34) {
                    be0 = bbase[(k + 2) * 256];
                    be1 = bbase[(k + 2) * 256 + 32];
                }
                acc00 = __builtin_amdgcn_mfma_f32_32x32x16_bf16(a0, bc0, acc00, 0, 0, 0);
                acc01 = __builtin_amdgcn_mfma_f32_32x32x16_bf16(a0, bc1, acc01, 0, 0, 0);
                acc10 = __builtin_amdgcn_mfma_f32_32x32x16_bf16(a1, bc0, acc10, 0, 0, 0);
                acc11 = __builtin_amdgcn_mfma_f32_32x32x16_bf16(a1, bc1, acc11, 0, 0, 0);
                a0 = an0; a1 = an1;
                bc0 = bd0; bc1 = bd1;
                bd0 = be0; bd1 = be1;
            }

            // re-prime B pipeline for next iteration (L1-resident)
            bc0 = bbase[0];   bc1 = bbase[32];
            bd0 = bbase[256]; bd1 = bbase[256 + 32];

            // ---- epilogue: bias + oc-pair min, butterfly reduce over l31
            float v[32];
            #pragma unroll
            for (int reg = 0; reg < 16; ++reg) {
                v[reg]      = fminf(acc00[reg] + bv0, acc01[reg] + bv1);  // m-tile 0
                v[16 + reg] = fminf(acc10[reg] + bv0, acc11[reg] + bv1);  // m-tile 1
            }
            #pragma unroll
            for (int mbit = 1; mbit <= 16; mbit <<= 1) {
                const int cnt = 16 / mbit;
                bool up = (l31 & mbit) != 0;
                #pragma unroll
                for (int j = 0; j < cnt; ++j) {
                    float send = up ? v[j] : v[j + cnt];
                    float recv = __shfl_xor(send, mbit, 64);
                    float mine = up ? v[j + cnt] : v[j];
                    v[j] = fminf(mine, recv);
                }
            }
            // lane l31 holds the reduced value for ridx = bitrev5(l31):
            // tile = ridx>>4, reg = ridx&15, m = (reg&3)+8*(reg>>2)+4*hi
            {
                int ridx = ((l31 & 1) << 4) | ((l31 & 2) << 2) | (l31 & 4) |
                           ((l31 & 8) >> 2) | ((l31 & 16) >> 4);
                int mm = ridx & 15;
                int px = ((ridx >> 4) << 5) + (mm & 3) + ((mm >> 2) << 3) + (hi << 2);
                obuf[nh * 128 + r * 64 + px] = v[0];
            }
        }

        __syncthreads();   // bar1: new slots + obuf visible

        if (tid < 128) {
            float x = fminf(obuf[tid], obuf[128 + tid]);
            x = tanhf(tanhf(x));
            const int col = tid & 63, row = tid >> 6;
            const int oh = (p0 + it) * 2 + row;
            if (ow0 + col < 254)
                out[((size_t)b * 254 + oh) * 254 + ow0 + col] = x;
        }

        __syncthreads();   // bar2: obuf reusable; producers may start next stage

        s0 += 2; if (s0 >= 6) s0 -= 6;
    }
}

extern "C" void kernel_launch(void* const* d_in, const int* in_sizes, int n_in,
                              void* d_out, int out_size, void* d_ws, size_t ws_size,
                              hipStream_t stream) {
    const float* x  = (const float*)d_in[0];   // (16,64,256,256)
    const float* wg = (const float*)d_in[1];   // (128,64,3,3)
    const float* bs = (const float*)d_in[2];   // (128,)
    float* out = (float*)d_out;                // (16,1,254,254)
    short* wsB = (short*)d_ws;                 // needs 147456 B

    wtrans<<<72, 256, 0, stream>>>(wg, wsB);
    dim3 grid(4, 8, 16);   // ow tiles, oh-pair groups (16 pairs each), batch
    conv_min_tanh_mfma<<<grid, 512, 0, stream>>>(x, wsB, bs, out);
}